// Round 14
// baseline (284.698 us; speedup 1.0000x reference)
//
#include <hip/hip_runtime.h>
#include <math.h>

#define Bsz 64
#define Nn  256
#define Hh  1024
#define NK  768

typedef __bf16 bf16;
typedef bf16 bf16x4 __attribute__((ext_vector_type(4)));
typedef bf16 bf16x8 __attribute__((ext_vector_type(8)));
typedef float floatx4 __attribute__((ext_vector_type(4)));

#define KT_ROWS   1026          // kTp rows per batch: h = -1 .. 1024
#define KT_BSTRIDE (KT_ROWS * 256)   // 262656 elements per batch

__device__ __forceinline__ void gl_lds16(const bf16* g, bf16* l) {
    __builtin_amdgcn_global_load_lds(
        (__attribute__((address_space(1))) void*)(g),
        (__attribute__((address_space(3))) void*)(l), 16, 0, 0);
}
__device__ __forceinline__ void gl_lds16f(const float* g, float* l) {
    __builtin_amdgcn_global_load_lds(
        (__attribute__((address_space(1))) void*)(g),
        (__attribute__((address_space(3))) void*)(l), 16, 0, 0);
}

// ---------------------------------------------------------------------------
// Transpose: kin[b][i][h] fp32 -> kTp[b][h+1][i] bf16. Tile 64i x 128h.
// (unchanged)
// ---------------------------------------------------------------------------
__global__ __launch_bounds__(256) void transpose_kernel(
    const float* __restrict__ kin, bf16* __restrict__ kTp)
{
    __shared__ float Tf[64 * 128];   // 32 KB
    const int tid = threadIdx.x;
    const int bid = blockIdx.x;
    const int hb = bid & 7, ib = (bid >> 3) & 3, b = bid >> 5;
    const int i0 = ib * 64, h0 = hb * 128;
    const float* src = kin + ((size_t)b << 18);
    bf16* dstb = kTp + (size_t)b * KT_BSTRIDE;

    if (hb == 0 && ib == 0) {
        dstb[tid] = (bf16)0.f;                       // h = -1 row
        dstb[(size_t)1025 * 256 + tid] = (bf16)0.f;  // h = 1024 row
    }
    #pragma unroll
    for (int j = 0; j < 8; ++j) {
        int c  = tid + j * 256;          // 0..2047
        int il = c >> 5;                 // i-local 0..63
        int hq = (c & 31) ^ j;           // swizzled h-quad
        gl_lds16f(src + (size_t)(i0 + il) * Hh + h0 + hq * 4, Tf + c * 4);
    }
    __syncthreads();
    const int q = tid & 7;
    #pragma unroll
    for (int p = 0; p < 4; ++p) {
        int hl = (tid >> 3) + p * 32;    // h-local 0..127
        bf16x8 o;
        #pragma unroll
        for (int j = 0; j < 8; ++j) {
            int i = q * 8 + j;           // i>>3 == q
            float v = Tf[i * 128 + (((hl >> 2) ^ q) << 2) + (hl & 3)];
            o[j] = (bf16)v;
        }
        *(bf16x8*)&dstb[(size_t)(h0 + hl + 1) * 256 + i0 + q * 8] = o;
    }
}

// ---------------------------------------------------------------------------
// Stage 1 v4 (fused cast, conflict-free, pipelined):
//  - tile 128x96, grid 1024 = 8 XCD x (16 panels x 8 col-blocks) -> 4 blk/CU
//  - BK=32, staging pitch 40 bf16 (80 B): fragment-read banks = row*20 mod 32
//    -> 2-way max (free). Reg-staging allows padding (no gl_lds constraint).
//  - single-barrier k-loop: load(k+1) -> MFMA(k) -> cvt+write(k+1 -> other
//    buf) -> barrier. Load latency hides under the 12 MFMAs + barrier.
// ---------------------------------------------------------------------------
__global__ __launch_bounds__(256) void gemm1_mfma(
    const float* __restrict__ A,    // f fp32 [16384][1024]
    const float* __restrict__ Bw,   // W_lin fp32 [768][1024]
    const float* __restrict__ bias,
    bf16* __restrict__ wgt3)        // [64*3][256][256]
{
    __shared__ bf16 smem[17920];    // dbuf[2][ A 128x40 | B 96x40 ]; epi Cs[128][104]
    const int tid  = threadIdx.x;
    const int wave = tid >> 6, lane = tid & 63;
    const int bid = blockIdx.x;
    const int xcd = bid & 7, loc = bid >> 3;      // loc 0..127
    const int ry  = (xcd << 4) | (loc >> 3);      // row-panel 0..127 (co-XCD)
    const int cx  = loc & 7;                      // col-block 0..7 (consecutive)
    const int row0 = ry * 128;
    const int col0 = cx * 96;

    // A: 128 rows x 8 fp32x4-chunks = 1024 -> 4/thread; B: 96x8 = 768 -> 3/thread
    const float* gA[4]; int lA[4];
    #pragma unroll
    for (int j = 0; j < 4; ++j) {
        int c = tid + j * 256, row = c >> 3, kq = c & 7;
        gA[j] = A + (size_t)(row0 + row) * Hh + kq * 4;
        lA[j] = row * 40 + kq * 4;                // padded pitch 40
    }
    const float* gB[3]; int lB[3];
    #pragma unroll
    for (int j = 0; j < 3; ++j) {
        int c = tid + j * 256, row = c >> 3, kq = c & 7;
        gB[j] = Bw + (size_t)(col0 + row) * Hh + kq * 4;
        lB[j] = 5120 + row * 40 + kq * 4;
    }

    const int wm = wave & 1, wn = wave >> 1;
    const int fm = lane & 15, koct = (lane >> 4) * 8;

    floatx4 zero = {0.f, 0.f, 0.f, 0.f};
    floatx4 acc[4][3];
    #pragma unroll
    for (int i = 0; i < 4; ++i)
        #pragma unroll
        for (int j = 0; j < 3; ++j) acc[i][j] = zero;

    // prologue: k-step 0 -> buf 0
    float4 av[4]; float4 bv[3];
    #pragma unroll
    for (int j = 0; j < 4; ++j) av[j] = *(const float4*)(gA[j]);
    #pragma unroll
    for (int j = 0; j < 3; ++j) bv[j] = *(const float4*)(gB[j]);
    #pragma unroll
    for (int j = 0; j < 4; ++j) {
        bf16x4 o = {(bf16)av[j].x, (bf16)av[j].y, (bf16)av[j].z, (bf16)av[j].w};
        *(bf16x4*)&smem[lA[j]] = o;
    }
    #pragma unroll
    for (int j = 0; j < 3; ++j) {
        bf16x4 o = {(bf16)bv[j].x, (bf16)bv[j].y, (bf16)bv[j].z, (bf16)bv[j].w};
        *(bf16x4*)&smem[lB[j]] = o;
    }
    __syncthreads();

    int cur = 0;
    for (int ks = 0; ks < 32; ++ks) {
        if (ks < 31) {                        // issue next step's loads FIRST
            const int ko = (ks + 1) * 32;
            #pragma unroll
            for (int j = 0; j < 4; ++j) av[j] = *(const float4*)(gA[j] + ko);
            #pragma unroll
            for (int j = 0; j < 3; ++j) bv[j] = *(const float4*)(gB[j] + ko);
        }
        const int cb = cur * 8960;
        bf16x8 af[4], bfr[3];
        #pragma unroll
        for (int mt = 0; mt < 4; ++mt)
            af[mt] = *(const bf16x8*)&smem[cb + (wm * 64 + mt * 16 + fm) * 40 + koct];
        #pragma unroll
        for (int nt = 0; nt < 3; ++nt)
            bfr[nt] = *(const bf16x8*)&smem[cb + 5120 + (wn * 48 + nt * 16 + fm) * 40 + koct];
        #pragma unroll
        for (int mt = 0; mt < 4; ++mt)
            #pragma unroll
            for (int nt = 0; nt < 3; ++nt)
                acc[mt][nt] = __builtin_amdgcn_mfma_f32_16x16x32_bf16(
                    af[mt], bfr[nt], acc[mt][nt], 0, 0, 0);
        if (ks < 31) {                        // write to the OTHER buffer
            const int ob = (cur ^ 1) * 8960;
            #pragma unroll
            for (int j = 0; j < 4; ++j) {
                bf16x4 o = {(bf16)av[j].x, (bf16)av[j].y, (bf16)av[j].z, (bf16)av[j].w};
                *(bf16x4*)&smem[ob + lA[j]] = o;
            }
            #pragma unroll
            for (int j = 0; j < 3; ++j) {
                bf16x4 o = {(bf16)bv[j].x, (bf16)bv[j].y, (bf16)bv[j].z, (bf16)bv[j].w};
                *(bf16x4*)&smem[ob + lB[j]] = o;
            }
        }
        __syncthreads();                      // one barrier per k-step
        cur ^= 1;
    }

    // Epilogue: acc -> Cs[128][96] (pitch 104), +bias, unscramble to wgt3.
    const int b  = row0 >> 8;
    const int nb = row0 & 255;
    bf16* Cs = smem;
    #pragma unroll
    for (int nt = 0; nt < 3; ++nt) {
        int c = wn * 48 + nt * 16 + fm;
        float bl = bias[col0 + c];
        #pragma unroll
        for (int mt = 0; mt < 4; ++mt) {
            int rb = wm * 64 + mt * 16 + (lane >> 4) * 4;
            #pragma unroll
            for (int r = 0; r < 4; ++r)
                Cs[(rb + r) * 104 + c] = (bf16)(acc[mt][nt][r] + bl);
        }
    }
    __syncthreads();
    const int i0 = cx * 32;
    #pragma unroll
    for (int j = 0; j < 6; ++j) {
        int s = tid + j * 256;               // 0..1535
        int t = s >> 9, rem = s & 511, n = rem >> 2, q8 = rem & 3;
        bf16x8 v;
        #pragma unroll
        for (int u = 0; u < 8; ++u)
            v[u] = Cs[n * 104 + (q8 * 8 + u) * 3 + t];
        *(bf16x8*)&wgt3[((size_t)(b * 3 + t) << 16) + ((size_t)(nb + n) << 8) + i0 + q8 * 8] = v;
    }
}

// ---------------------------------------------------------------------------
// Stage 2 v3: h-tile 128, grid 2048, XCD-swizzled, 2-barrier. (unchanged)
// ---------------------------------------------------------------------------
__global__ __launch_bounds__(256) void conv_mfma(
    const bf16* __restrict__ kTp,   // [64][1026][256]
    const bf16* __restrict__ wgt3,  // [64*3][256][256]
    bf16* __restrict__ cbuf)        // [64][256][1024] bf16
{
    __shared__ bf16 As[6144];       // [t][o(64)][i(32)]  12 KB
    __shared__ bf16 Ks[4160];       // [row(130)][i(32)]  8.3 KB
    const int tid  = threadIdx.x;
    const int wave = tid >> 6, lane = tid & 63;
    const int bid = blockIdx.x;
    const int xcd = bid & 7, loc = bid >> 3;      // loc 0..255
    const int b   = (xcd << 3) | (loc >> 5);      // 0..63
    const int rem = loc & 31;
    const int o0  = (rem >> 3) * 64;              // 4 o-tiles
    const int h0  = (rem & 7) * 128;              // 8 h-tiles
    const int wm = wave & 1, wn = wave >> 1;
    const int fm = lane & 15, koct = (lane >> 4) * 8;

    const bf16* gA[3]; bf16* lA[3];
    #pragma unroll
    for (int j = 0; j < 3; ++j) {
        int s = tid + j * 256;               // 0..767
        int t = s >> 8, r2 = s & 255, o = r2 >> 2, iq = r2 & 3;
        gA[j] = wgt3 + ((size_t)(b * 3 + t) << 16) + ((size_t)(o0 + o) << 8) + iq * 8;
        lA[j] = As + s * 8;
    }
    const bf16* kb = kTp + (size_t)b * KT_BSTRIDE;
    const bf16* gK[2]; bf16* lK[2];
    #pragma unroll
    for (int j = 0; j < 2; ++j) {
        int s = tid + j * 256;               // 0..511 -> rows 0..127
        int r = s >> 2, quad = s & 3;
        gK[j] = kb + (size_t)(h0 + r) * 256 + quad * 8;
        lK[j] = Ks + s * 8;
    }
    const bf16* gH = kb + (size_t)(h0 + 128 + (tid >> 2)) * 256 + (tid & 3) * 8;
    const int lH = (128 + (tid >> 2)) * 32 + (tid & 3) * 8;

    floatx4 zero = {0.f, 0.f, 0.f, 0.f};
    floatx4 acc[2][4];
    #pragma unroll
    for (int i = 0; i < 2; ++i)
        #pragma unroll
        for (int j = 0; j < 4; ++j) acc[i][j] = zero;

    for (int ic = 0; ic < 8; ++ic) {
        const int i0 = ic * 32;
        __syncthreads();
        #pragma unroll
        for (int j = 0; j < 3; ++j) gl_lds16(gA[j] + i0, lA[j]);
        #pragma unroll
        for (int j = 0; j < 2; ++j) gl_lds16(gK[j] + i0, lK[j]);
        if (tid < 8) {
            bf16x8 v = *(const bf16x8*)(gH + i0);
            *(bf16x8*)&Ks[lH] = v;
        }
        __syncthreads();
        #pragma unroll
        for (int t = 0; t < 3; ++t) {
            bf16x8 af[2], bfr[4];
            #pragma unroll
            for (int mt = 0; mt < 2; ++mt)
                af[mt] = *(const bf16x8*)&As[t * 2048 + (wm * 32 + mt * 16 + fm) * 32 + koct];
            #pragma unroll
            for (int nt = 0; nt < 4; ++nt)
                bfr[nt] = *(const bf16x8*)&Ks[(wn * 64 + nt * 16 + fm + t) * 32 + koct];
            #pragma unroll
            for (int mt = 0; mt < 2; ++mt)
                #pragma unroll
                for (int nt = 0; nt < 4; ++nt)
                    acc[mt][nt] = __builtin_amdgcn_mfma_f32_16x16x32_bf16(
                        af[mt], bfr[nt], acc[mt][nt], 0, 0, 0);
        }
    }

    #pragma unroll
    for (int mt = 0; mt < 2; ++mt) {
        int o = o0 + wm * 32 + mt * 16 + (lane >> 4) * 4;
        #pragma unroll
        for (int nt = 0; nt < 4; ++nt) {
            int h = h0 + wn * 64 + nt * 16 + fm;
            #pragma unroll
            for (int r = 0; r < 4; ++r)
                cbuf[((size_t)(b * 256 + o + r) << 10) + h] = (bf16)acc[mt][nt][r];
        }
    }
}

// ---------------------------------------------------------------------------
// Stage 3: LayerNorm, 2048 blocks x 8 rows.  (unchanged)
// ---------------------------------------------------------------------------
__global__ __launch_bounds__(256) void ln_kernel(
    const bf16* __restrict__ cbuf, const float* __restrict__ gamma,
    const float* __restrict__ beta, float* __restrict__ out)
{
    const int tid  = threadIdx.x;
    const int t    = tid & 127;
    const int half = tid >> 7;
    bf16x8 v[4];
    #pragma unroll
    for (int it = 0; it < 4; ++it) {
        const int row = (blockIdx.x << 3) + it * 2 + half;
        v[it] = *(const bf16x8*)(cbuf + ((size_t)row << 10) + t * 8);
    }
    float4 g0  = ((const float4*)gamma)[t * 2];
    float4 g1  = ((const float4*)gamma)[t * 2 + 1];
    float4 be0 = ((const float4*)beta)[t * 2];
    float4 be1 = ((const float4*)beta)[t * 2 + 1];
    __shared__ float r1[2][4], r2[2][4];
    #pragma unroll
    for (int it = 0; it < 4; ++it) {
        const int row = (blockIdx.x << 3) + it * 2 + half;
        float x[8];
        float s1 = 0.f, s2 = 0.f;
        #pragma unroll
        for (int u = 0; u < 8; ++u) {
            x[u] = (float)v[it][u];
            s1 += x[u];
            s2 += x[u] * x[u];
        }
        #pragma unroll
        for (int m = 1; m < 64; m <<= 1) {
            s1 += __shfl_xor(s1, m, 64);
            s2 += __shfl_xor(s2, m, 64);
        }
        const int p = it & 1;
        if ((tid & 63) == 0) { r1[p][tid >> 6] = s1; r2[p][tid >> 6] = s2; }
        __syncthreads();
        float S1 = r1[p][2 * half] + r1[p][2 * half + 1];
        float S2 = r2[p][2 * half] + r2[p][2 * half + 1];
        float mu   = S1 * (1.0f / 1024.0f);
        float var  = S2 * (1.0f / 1024.0f) - mu * mu;
        float rstd = rsqrtf(var + 1e-5f);
        float4 o0, o1;
        o0.x = (x[0] - mu) * rstd * g0.x + be0.x;
        o0.y = (x[1] - mu) * rstd * g0.y + be0.y;
        o0.z = (x[2] - mu) * rstd * g0.z + be0.z;
        o0.w = (x[3] - mu) * rstd * g0.w + be0.w;
        o1.x = (x[4] - mu) * rstd * g1.x + be1.x;
        o1.y = (x[5] - mu) * rstd * g1.y + be1.y;
        o1.z = (x[6] - mu) * rstd * g1.z + be1.z;
        o1.w = (x[7] - mu) * rstd * g1.w + be1.w;
        float* orow = out + ((size_t)row << 10) + t * 8;
        ((float4*)orow)[0] = o0;
        ((float4*)orow)[1] = o1;
    }
}

extern "C" void kernel_launch(void* const* d_in, const int* in_sizes, int n_in,
                              void* d_out, int out_size, void* d_ws, size_t ws_size,
                              hipStream_t stream) {
    const float* f     = (const float*)d_in[0];
    const float* kin   = (const float*)d_in[1];
    const float* W_lin = (const float*)d_in[2];
    const float* b_lin = (const float*)d_in[3];
    const float* gamma = (const float*)d_in[4];
    const float* beta  = (const float*)d_in[5];
    float* out = (float*)d_out;

    char* ws = (char*)d_ws;
    bf16* cbuf = (bf16*)(ws);                   // 33.55 MB
    bf16* kTp  = (bf16*)(ws + 35127296);        // 33.62 MB
    bf16* wgt3 = (bf16*)(ws + 68747264);        // 25.17 MB

    transpose_kernel<<<2048, 256, 0, stream>>>(kin, kTp);
    gemm1_mfma<<<1024, 256, 0, stream>>>(f, W_lin, b_lin, wgt3);
    conv_mfma<<<2048, 256, 0, stream>>>(kTp, wgt3, cbuf);
    ln_kernel<<<2048, 256, 0, stream>>>(cbuf, gamma, beta, out);
}